// Round 12
// baseline (395.270 us; speedup 1.0000x reference)
//
#include <hip/hip_runtime.h>

#define NN 50000
#define EE 600000
#define DD 128
#define GG 256
#define LL 5
#define OO 10
#define BN_EPS 1e-5f
#define CPAD 515      // 512 combos + 3 sentinel (-1e30) rows (slot 0x02020202 -> cidx 514)
#define ESTRIDE 40    // fixed CSR slots per node (P(deg>40)~1e-9 at lambda=12)

#define B_SCAT  2344                       // ceil(EE/256)
#define B_COMBO 1288                       // ceil(LL*CPAD*DD / 256)
#define B_WT    160                        // 10 mats x 16 (32x32) tiles
#define B_CVT   3125                       // NN*DD/8 / 256 (pure convert)
#define B_POOL  2048                       // 8 blocks per graph
#define B_PREP  (B_SCAT + B_COMBO + B_WT + B_CVT + B_POOL)  // 8965, coprime w/ 1021

typedef __attribute__((ext_vector_type(8))) short short8;
typedef __attribute__((ext_vector_type(16))) float float16;
typedef __attribute__((ext_vector_type(4))) unsigned uint4e;   // nontemporal-compatible
typedef __attribute__((ext_vector_type(2))) float float2v;     // v_pk_add_f32 carrier

__device__ __forceinline__ unsigned short f2b(float f) {   // fp32 -> bf16 RNE
    unsigned u = __float_as_uint(f);
    unsigned r = u + 0x7FFFu + ((u >> 16) & 1u);
    return (unsigned short)(r >> 16);
}
__device__ __forceinline__ unsigned pk2(float lo, float hi) {
    return (unsigned)f2b(lo) | ((unsigned)f2b(hi) << 16);
}
__device__ __forceinline__ float blo(unsigned u) { return __uint_as_float(u << 16); }
__device__ __forceinline__ float bhi(unsigned u) { return __uint_as_float(u & 0xFFFF0000u); }

__device__ __forceinline__ float2v up2(unsigned u) {       // 2 packed bf16 -> float2
    float2v r;
    r.x = __uint_as_float(u << 16);
    r.y = __uint_as_float(u & 0xFFFF0000u);
    return r;
}
// packed accumulate: acc[i] += max(x2 + c2, 0) ; adds emit v_pk_add_f32.
// NOTE (round-11 lesson): slot->lane mapping is {4eg..4eg+3}, so NO deg-based
// skipping of sub-gathers is valid — sentinels already make all 16 slots safe.
__device__ __forceinline__ void acc8v(float2v* acc, uint4 xv, uint4 cv) {
    const float2v z = {0.f, 0.f};
    acc[0] += __builtin_elementwise_max(up2(xv.x) + up2(cv.x), z);
    acc[1] += __builtin_elementwise_max(up2(xv.y) + up2(cv.y), z);
    acc[2] += __builtin_elementwise_max(up2(xv.z) + up2(cv.z), z);
    acc[3] += __builtin_elementwise_max(up2(xv.w) + up2(cv.w), z);
}

// == mega prep: edge-scatter | combo | Wt-transpose | cvt_x | pool0 (striped) ==
__launch_bounds__(256)
__global__ void prep(const float* __restrict__ x, const int* __restrict__ ei,
                     const int* __restrict__ eattr, const int* __restrict__ batch,
                     const float* __restrict__ bond,
                     const float* __restrict__ w1, const float* __restrict__ w2,
                     unsigned* __restrict__ xb4, unsigned short* __restrict__ combo,
                     short* __restrict__ wt, int* __restrict__ epos,
                     unsigned* __restrict__ e_info, float* __restrict__ pooled0) {
    // bijective stripe: gcd(1021, 8965)=1 -> all sections co-resident
    const int bid = (int)(((long long)blockIdx.x * 1021) % B_PREP);
    const int t = threadIdx.x;
    if (bid < B_SCAT) {
        int e = bid * 256 + t;
        if (e < EE) {
            int dst = ei[EE + e];
            int slot = atomicAdd(&epos[dst], 1);
            if (slot < ESTRIDE) {
                unsigned cidx = (unsigned)eattr[e * 3 + 0] | ((unsigned)eattr[e * 3 + 1] << 3)
                              | ((unsigned)eattr[e * 3 + 2] << 6);
                e_info[dst * ESTRIDE + slot] = (unsigned)ei[e] | (cidx << 16);
            }
        }
    } else if (bid < B_SCAT + B_COMBO) {
        int e = (bid - B_SCAT) * 256 + t;
        if (e < LL * CPAD * DD) {
            int l = e / (CPAD * DD), rem = e - l * (CPAD * DD);
            int c = rem / DD, d = rem - c * DD;
            float s;
            if (c >= 512) s = -1e30f;                     // sentinel rows: relu(x+s)==0
            else {
                const float* b_ = bond + (size_t)l * 3 * 8 * DD;
                s = b_[(c & 7) * DD + d] + b_[(8 + ((c >> 3) & 7)) * DD + d]
                  + b_[(16 + (c >> 6)) * DD + d];
            }
            combo[e] = f2b(s);
        }
    } else if (bid < B_SCAT + B_COMBO + B_WT) {
        __shared__ float tile[32][33];
        int b = bid - B_SCAT - B_COMBO;
        int mat = b >> 4, tl = b & 15;
        int k0 = (tl >> 2) * 32, c0 = (tl & 3) * 32;
        const float* W = (mat < 5) ? (w1 + (size_t)mat * DD * DD)
                                   : (w2 + (size_t)(mat - 5) * DD * DD);
        int j = t & 31, q = t >> 5;
#pragma unroll
        for (int rr = 0; rr < 4; ++rr) {
            int row = q + rr * 8;
            tile[row][j] = W[(size_t)(k0 + row) * DD + c0 + j];
        }
        __syncthreads();
#pragma unroll
        for (int rr = 0; rr < 4; ++rr) {
            int cr = q + rr * 8;
            wt[(size_t)mat * DD * DD + (size_t)(c0 + cr) * DD + k0 + j] = (short)f2b(tile[j][cr]);
        }
    } else if (bid < B_SCAT + B_COMBO + B_WT + B_CVT) {
        int gid = (bid - (B_SCAT + B_COMBO + B_WT)) * 256 + t;
        const float4* xp = (const float4*)(x + (size_t)gid * 8);
        float4 a = xp[0], c4 = xp[1];
        uint4 o;
        o.x = pk2(a.x, a.y); o.y = pk2(a.z, a.w);
        o.z = pk2(c4.x, c4.y); o.w = pk2(c4.z, c4.w);
        ((uint4*)xb4)[gid] = o;
    } else {
        __shared__ float sm[DD];
        int b = bid - (B_SCAT + B_COMBO + B_WT + B_CVT);
        int g = b >> 3, s = b & 7;
        int r0, r1;
        {
            int lo = 0, hi = NN;
            while (lo < hi) { int m = (lo + hi) >> 1; if (batch[m] < g) lo = m + 1; else hi = m; }
            r0 = lo;
            lo = 0; hi = NN;
            while (lo < hi) { int m = (lo + hi) >> 1; if (batch[m] < g + 1) lo = m + 1; else hi = m; }
            r1 = lo;
        }
        int col = t & 127, par = t >> 7;
        float ssum = 0.f;
        for (int r = r0 + s * 2 + par; r < r1; r += 16) ssum += x[(size_t)r * DD + col];
        if (par == 0) sm[col] = ssum;
        __syncthreads();
        if (par == 1) {
            float v = sm[col] + ssum;
            if (v != 0.f) atomicAdd(&pooled0[(size_t)g * DD + col], v);
        }
    }
}

// ====== fused layer: CSR aggregation (phase A) + conv/BN/pool (phase B) ======
// Phase A = round-10 structure (passed, 49.3us) + packed-fp32 accumulate
// (float2v -> v_pk_add_f32; ~20-25% fewer VALU ops in the dominant chain).
// All 16 slots are always gathered+accumulated (sentinel slots contribute 0).
__launch_bounds__(256, 3)
__global__ void layer_fused(const unsigned short* __restrict__ xin,
                            const int* __restrict__ epos,
                            const unsigned* __restrict__ e_info,
                            const unsigned short* __restrict__ combo,
                            const short* __restrict__ Wt1, const short* __restrict__ Wt2,
                            const float* __restrict__ b1, const float* __restrict__ g1,
                            const float* __restrict__ be1, const float* __restrict__ m1,
                            const float* __restrict__ v1,
                            const float* __restrict__ b2, const float* __restrict__ g2,
                            const float* __restrict__ be2, const float* __restrict__ m2,
                            const float* __restrict__ v2,
                            const int* __restrict__ batch,
                            unsigned short* __restrict__ xout,
                            float* __restrict__ pool_slot) {
    __shared__ short As[32 * 136];
    __shared__ int sbg[32];
    const int tid  = threadIdx.x;
    const int lane = tid & 63;
    const int wave = tid >> 6;
    const int row0 = blockIdx.x * 32;
    const int gmin = batch[row0];

    if (tid < 32) {
        int row = row0 + tid;
        sbg[tid] = (row < NN) ? batch[row] - gmin : -1;
    }

    // ---- phase A ----
    const int eg = lane >> 4;            // slot sub-group 0..3
    const int f  = (lane & 15) * 8;      // feature offset
    const int node0 = row0 + wave * 8;

    // deg prefetch: lane j holds epos[node0 + (j&7)]
    int degp;
    {
        int nk = node0 + (lane & 7);
        if (nk >= NN) nk = NN - 1;
        degp = epos[nk];
    }
    // e_info prefetch: one dwordx4 per node (this lane's slots {4eg..4eg+3})
    uint4e ev[8];
#pragma unroll
    for (int k = 0; k < 8; ++k) {
        int nk = node0 + k;
        if (nk >= NN) nk = NN - 1;
        ev[k] = __builtin_nontemporal_load(
            (const uint4e*)&e_info[(size_t)nk * ESTRIDE + eg * 4]);
    }

    // double-buffered gather registers (+ prefetched self row for the residual)
    uint4 xg[2][4], cg[2][4], sf[2];
#define GATHER(B, K)                                                            \
    do {                                                                        \
        xg[B][0] = *(const uint4*)&xin[(size_t)(ev[K].x & 0xFFFFu) * DD + f];   \
        cg[B][0] = *(const uint4*)&combo[(size_t)(ev[K].x >> 16) * DD + f];     \
        xg[B][1] = *(const uint4*)&xin[(size_t)(ev[K].y & 0xFFFFu) * DD + f];   \
        cg[B][1] = *(const uint4*)&combo[(size_t)(ev[K].y >> 16) * DD + f];     \
        xg[B][2] = *(const uint4*)&xin[(size_t)(ev[K].z & 0xFFFFu) * DD + f];   \
        cg[B][2] = *(const uint4*)&combo[(size_t)(ev[K].z >> 16) * DD + f];     \
        xg[B][3] = *(const uint4*)&xin[(size_t)(ev[K].w & 0xFFFFu) * DD + f];   \
        cg[B][3] = *(const uint4*)&combo[(size_t)(ev[K].w >> 16) * DD + f];     \
        int nkk = node0 + (K); if (nkk >= NN) nkk = NN - 1;                     \
        sf[B] = *(const uint4*)&xin[(size_t)nkk * DD + f];                      \
    } while (0)

    GATHER(0, 0);
    __builtin_amdgcn_sched_barrier(0);   // pin buffer-0 loads before the loop
#pragma unroll
    for (int k = 0; k < 8; ++k) {
        const int cur = k & 1;
        const int nxt = cur ^ 1;
        if (k < 7) {
            GATHER(nxt, k + 1);          // issue next node's gathers NOW
            __builtin_amdgcn_sched_barrier(0);  // forbid sinking them below
        }

        float2v acc[4];
#pragma unroll
        for (int i = 0; i < 4; ++i) { acc[i].x = 0.f; acc[i].y = 0.f; }
        acc8v(acc, xg[cur][0], cg[cur][0]);
        acc8v(acc, xg[cur][1], cg[cur][1]);
        acc8v(acc, xg[cur][2], cg[cur][2]);
        acc8v(acc, xg[cur][3], cg[cur][3]);

        const int nl = wave * 8 + k;
        const int node = row0 + nl;
        int deg = __shfl(degp, k, 64);
        if (deg > 16 && node < NN) {     // ~10% of nodes; slow path
            if (deg > ESTRIDE) deg = ESTRIDE;
            const int base = node * ESTRIDE;
            const int pe = base + ((deg + 7) & ~7);
            for (int p = base + 16; p < pe; p += 8) {
                // 8 slots; this lane takes {p+2eg, p+2eg+1}
                uint2 jv = *(const uint2*)&e_info[p + eg * 2];
                uint4 ax0 = *(const uint4*)&xin[(size_t)(jv.x & 0xFFFFu) * DD + f];
                uint4 ac0 = *(const uint4*)&combo[(size_t)(jv.x >> 16) * DD + f];
                uint4 ax1 = *(const uint4*)&xin[(size_t)(jv.y & 0xFFFFu) * DD + f];
                uint4 ac1 = *(const uint4*)&combo[(size_t)(jv.y >> 16) * DD + f];
                acc8v(acc, ax0, ac0);
                acc8v(acc, ax1, ac1);
            }
        }

        // reduce across the 4 slot sub-groups (lanes differing in bits 4,5)
#pragma unroll
        for (int i = 0; i < 4; ++i) {
            acc[i].x += __shfl_xor(acc[i].x, 16, 64);
            acc[i].x += __shfl_xor(acc[i].x, 32, 64);
            acc[i].y += __shfl_xor(acc[i].y, 16, 64);
            acc[i].y += __shfl_xor(acc[i].y, 32, 64);
        }
        if (lane < 16) {
            if (node < NN) {
                uint4 self = sf[cur];
                float2v r0 = acc[0] + up2(self.x);
                float2v r1 = acc[1] + up2(self.y);
                float2v r2 = acc[2] + up2(self.z);
                float2v r3 = acc[3] + up2(self.w);
                uint4 o;
                o.x = pk2(r0.x, r0.y);
                o.y = pk2(r1.x, r1.y);
                o.z = pk2(r2.x, r2.y);
                o.w = pk2(r3.x, r3.y);
                *(uint4*)&As[nl * 136 + f] = o;
            } else {
                *(uint4*)&As[nl * 136 + f] = make_uint4(0, 0, 0, 0);
            }
        }
    }
#undef GATHER
    __syncthreads();

    // ---- phase B: conv + BN + pooling (reads As) ----
    const int col   = wave * 32 + (lane & 31);
    const int khalf = (lane >> 5) * 8;
    const int arow  = lane & 31;
    const int rbase = 4 * (lane >> 5);

    short8 bf[8];
#pragma unroll
    for (int ch = 0; ch < 8; ++ch)
        bf[ch] = *(const short8*)&Wt1[col * DD + ch * 16 + khalf];

    const float sc1 = g1[col] * rsqrtf(v1[col] + BN_EPS);
    const float sh1 = fmaf(b1[col] - m1[col], sc1, be1[col]);
    const float sc2 = g2[col] * rsqrtf(v2[col] + BN_EPS);
    const float sh2 = fmaf(b2[col] - m2[col], sc2, be2[col]);

    float16 acc0 = {0.f,0.f,0.f,0.f,0.f,0.f,0.f,0.f,0.f,0.f,0.f,0.f,0.f,0.f,0.f,0.f};
#pragma unroll
    for (int ch = 0; ch < 8; ++ch) {
        short8 a0 = *(const short8*)&As[arow * 136 + ch * 16 + khalf];
        acc0 = __builtin_amdgcn_mfma_f32_32x32x16_bf16(a0, bf[ch], acc0, 0, 0, 0);
    }

#pragma unroll
    for (int ch = 0; ch < 8; ++ch)
        bf[ch] = *(const short8*)&Wt2[col * DD + ch * 16 + khalf];

    __syncthreads();
#pragma unroll
    for (int r = 0; r < 16; ++r) {
        int rl = (r & 3) + 8 * (r >> 2) + rbase;
        As[rl * 136 + col] = (short)f2b(fmaxf(fmaf(acc0[r], sc1, sh1), 0.f));
    }
    __syncthreads();

    acc0 = float16{0.f,0.f,0.f,0.f,0.f,0.f,0.f,0.f,0.f,0.f,0.f,0.f,0.f,0.f,0.f,0.f};
#pragma unroll
    for (int ch = 0; ch < 8; ++ch) {
        short8 a0 = *(const short8*)&As[arow * 136 + ch * 16 + khalf];
        acc0 = __builtin_amdgcn_mfma_f32_32x32x16_bf16(a0, bf[ch], acc0, 0, 0, 0);
    }

    float pg0 = 0.f, pg1 = 0.f, pg2 = 0.f, pg3 = 0.f;
#pragma unroll
    for (int r = 0; r < 16; ++r) {
        int rl  = (r & 3) + 8 * (r >> 2) + rbase;
        int row = row0 + rl;
        float v0 = fmaxf(fmaf(acc0[r], sc2, sh2), 0.f);
        if (row < NN) xout[(size_t)row * DD + col] = f2b(v0);
        int ga = sbg[rl];
        pg0 += (ga == 0) ? v0 : 0.f;
        pg1 += (ga == 1) ? v0 : 0.f;
        pg2 += (ga == 2) ? v0 : 0.f;
        pg3 += (ga == 3) ? v0 : 0.f;
    }
    pg0 += __shfl_down(pg0, 32);
    pg1 += __shfl_down(pg1, 32);
    pg2 += __shfl_down(pg2, 32);
    pg3 += __shfl_down(pg3, 32);
    if (lane < 32) {
        if (pg0 != 0.f)                  atomicAdd(&pool_slot[(gmin    ) * DD + col], pg0);
        if (pg1 != 0.f && gmin + 1 < GG) atomicAdd(&pool_slot[(gmin + 1) * DD + col], pg1);
        if (pg2 != 0.f && gmin + 2 < GG) atomicAdd(&pool_slot[(gmin + 2) * DD + col], pg2);
        if (pg3 != 0.f && gmin + 3 < GG) atomicAdd(&pool_slot[(gmin + 3) * DD + col], pg3);
    }
}

// ====== final head: out[g,:] = inv[g]*sum_l pooled_l@fcw_l + sum_l fcb_l ======
__launch_bounds__(64)
__global__ void head(const int* __restrict__ batch, const float* __restrict__ pooled,
                     const float* __restrict__ fcw, const float* __restrict__ fcb,
                     float* __restrict__ out) {
    int g = blockIdx.x, t = threadIdx.x;
    __shared__ float part[LL + 1][OO];
    int r0, r1;
    {
        int lo = 0, hi = NN;
        while (lo < hi) { int m = (lo + hi) >> 1; if (batch[m] < g) lo = m + 1; else hi = m; }
        r0 = lo;
        lo = 0; hi = NN;
        while (lo < hi) { int m = (lo + hi) >> 1; if (batch[m] < g + 1) lo = m + 1; else hi = m; }
        r1 = lo;
    }
    const float invg = 1.0f / fmaxf((float)(r1 - r0), 1.0f);
    if (t < (LL + 1) * OO) {
        int l = t / OO, o2 = t - l * OO;
        const float* p = pooled + ((size_t)l * GG + g) * DD;
        const float* w = fcw + (size_t)l * DD * OO + o2;
        float s = 0.f;
        for (int d2 = 0; d2 < DD; ++d2) s = fmaf(p[d2], w[(size_t)d2 * OO], s);
        part[l][o2] = s;
    }
    __syncthreads();
    if (t < OO) {
        float sp = 0.f, sb2 = 0.f;
#pragma unroll
        for (int l = 0; l < LL + 1; ++l) { sp += part[l][t]; sb2 += fcb[l * OO + t]; }
        out[g * OO + t] = sp * invg + sb2;
    }
}

extern "C" void kernel_launch(void* const* d_in, const int* in_sizes, int n_in,
                              void* d_out, int out_size, void* d_ws, size_t ws_size,
                              hipStream_t stream) {
    const float* x_in    = (const float*)d_in[0];
    const int*   ei      = (const int*)d_in[1];
    const int*   eattr   = (const int*)d_in[2];
    const int*   batch   = (const int*)d_in[3];
    const float* bond    = (const float*)d_in[4];
    const float* conv_w1 = (const float*)d_in[5];
    const float* conv_b1 = (const float*)d_in[6];
    const float* cbg     = (const float*)d_in[7];
    const float* cbb     = (const float*)d_in[8];
    const float* cbm     = (const float*)d_in[9];
    const float* cbv     = (const float*)d_in[10];
    const float* conv_w2 = (const float*)d_in[11];
    const float* conv_b2 = (const float*)d_in[12];
    const float* bg      = (const float*)d_in[13];
    const float* bb      = (const float*)d_in[14];
    const float* bm      = (const float*)d_in[15];
    const float* bv      = (const float*)d_in[16];
    const float* fcw     = (const float*)d_in[17];
    const float* fcb     = (const float*)d_in[18];
    float* out = (float*)d_out;

    // ---- workspace carve-up (16B-aligned chunks) ----
    char* base = (char*)d_ws;
    size_t o = 0;
    auto carve = [&](size_t bytes) { void* p = base + o; o += (bytes + 15) & ~(size_t)15; return p; };
    unsigned short* xbA    = (unsigned short*)carve((size_t)NN * DD * 2);
    unsigned short* xbB    = (unsigned short*)carve((size_t)NN * DD * 2);
    unsigned short* combo  = (unsigned short*)carve((size_t)LL * CPAD * DD * 2);
    short*          wt     = (short*)carve((size_t)10 * DD * DD * 2);
    // contiguous zero-region: epos | pooled[6][G][D] (slot 0 = pool0)
    const size_t ZBYTES = (size_t)NN * 4 + (size_t)(LL + 1) * GG * DD * 4;
    int*            epos   = (int*)carve(ZBYTES);
    float*          pooled = (float*)((char*)epos + (size_t)NN * 4);
    unsigned*       e_info = (unsigned*)carve((size_t)NN * ESTRIDE * 4);

    (void)hipMemsetAsync(epos, 0, ZBYTES, stream);
    (void)hipMemsetAsync(e_info, 0x02, (size_t)NN * ESTRIDE * 4, stream);  // sentinel fill

    prep<<<B_PREP, 256, 0, stream>>>(x_in, ei, eattr, batch, bond, conv_w1, conv_w2,
                                     (unsigned*)xbA, combo, wt, epos, e_info, pooled);

    const int layer_blocks = (NN + 31) / 32;    // 1563
    unsigned short* xcur = xbA;   // layer input (complete previous activation)
    unsigned short* xnxt = xbB;   // layer output (ping-pong; in-place would race)
    for (int i = 0; i < LL; ++i) {
        layer_fused<<<layer_blocks, 256, 0, stream>>>(
            xcur, epos, e_info, combo + (size_t)i * CPAD * DD,
            wt + (size_t)i * DD * DD, wt + (size_t)(5 + i) * DD * DD,
            conv_b1 + (size_t)i * DD, cbg + (size_t)i * DD, cbb + (size_t)i * DD,
            cbm + (size_t)i * DD, cbv + (size_t)i * DD,
            conv_b2 + (size_t)i * DD, bg + (size_t)i * DD, bb + (size_t)i * DD,
            bm + (size_t)i * DD, bv + (size_t)i * DD,
            batch, xnxt, pooled + (size_t)(i + 1) * GG * DD);
        unsigned short* tmp = xcur; xcur = xnxt; xnxt = tmp;
    }
    head<<<GG, 64, 0, stream>>>(batch, pooled, fcw, fcb, out);
}

// Round 13
// 382.678 us; speedup vs baseline: 1.0329x; 1.0329x over previous
//
#include <hip/hip_runtime.h>

#define NN 50000
#define EE 600000
#define DD 128
#define GG 256
#define LL 5
#define OO 10
#define BN_EPS 1e-5f
#define CPAD 515      // 512 combos + 3 sentinel (-1e30) rows (slot 0x02020202 -> cidx 514)
#define ESTRIDE 40    // fixed CSR slots per node (P(deg>40)~1e-9 at lambda=12)

#define B_SCAT  2344                       // ceil(EE/256)
#define B_COMBO 1288                       // ceil(LL*CPAD*DD / 256)
#define B_WT    160                        // 10 mats x 16 (32x32) tiles
#define B_CVT   3125                       // NN*DD/8 / 256 (pure convert)
#define B_POOL  2048                       // 8 blocks per graph
#define B_PREP  (B_SCAT + B_COMBO + B_WT + B_CVT + B_POOL)  // 8965, coprime w/ 1021

typedef __attribute__((ext_vector_type(8))) short short8;
typedef __attribute__((ext_vector_type(16))) float float16;
typedef __attribute__((ext_vector_type(4))) unsigned uint4e;

// opaque asm load: compiler cannot track or sink it; waitcnt is OURS to manage
#define GLD(dst, ptr) \
    asm volatile("global_load_dwordx4 %0, %1, off" : "=v"(dst) : "v"(ptr))

__device__ __forceinline__ unsigned short f2b(float f) {   // fp32 -> bf16 RNE
    unsigned u = __float_as_uint(f);
    unsigned r = u + 0x7FFFu + ((u >> 16) & 1u);
    return (unsigned short)(r >> 16);
}
__device__ __forceinline__ unsigned pk2(float lo, float hi) {
    return (unsigned)f2b(lo) | ((unsigned)f2b(hi) << 16);
}
__device__ __forceinline__ float blo(unsigned u) { return __uint_as_float(u << 16); }
__device__ __forceinline__ float bhi(unsigned u) { return __uint_as_float(u & 0xFFFF0000u); }

__device__ __forceinline__ void acc8(float* acc, uint4e xv, uint4e cv) {
    acc[0] += fmaxf(blo(xv.x) + blo(cv.x), 0.f);
    acc[1] += fmaxf(bhi(xv.x) + bhi(cv.x), 0.f);
    acc[2] += fmaxf(blo(xv.y) + blo(cv.y), 0.f);
    acc[3] += fmaxf(bhi(xv.y) + bhi(cv.y), 0.f);
    acc[4] += fmaxf(blo(xv.z) + blo(cv.z), 0.f);
    acc[5] += fmaxf(bhi(xv.z) + bhi(cv.z), 0.f);
    acc[6] += fmaxf(blo(xv.w) + blo(cv.w), 0.f);
    acc[7] += fmaxf(bhi(xv.w) + bhi(cv.w), 0.f);
}
__device__ __forceinline__ void acc8u(float* acc, uint4 xv, uint4 cv) {
    acc[0] += fmaxf(blo(xv.x) + blo(cv.x), 0.f);
    acc[1] += fmaxf(bhi(xv.x) + bhi(cv.x), 0.f);
    acc[2] += fmaxf(blo(xv.y) + blo(cv.y), 0.f);
    acc[3] += fmaxf(bhi(xv.y) + bhi(cv.y), 0.f);
    acc[4] += fmaxf(blo(xv.z) + blo(cv.z), 0.f);
    acc[5] += fmaxf(bhi(xv.z) + bhi(cv.z), 0.f);
    acc[6] += fmaxf(blo(xv.w) + blo(cv.w), 0.f);
    acc[7] += fmaxf(bhi(xv.w) + bhi(cv.w), 0.f);
}

// == mega prep: edge-scatter | combo | Wt-transpose | cvt_x | pool0 (striped) ==
__launch_bounds__(256)
__global__ void prep(const float* __restrict__ x, const int* __restrict__ ei,
                     const int* __restrict__ eattr, const int* __restrict__ batch,
                     const float* __restrict__ bond,
                     const float* __restrict__ w1, const float* __restrict__ w2,
                     unsigned* __restrict__ xb4, unsigned short* __restrict__ combo,
                     short* __restrict__ wt, int* __restrict__ epos,
                     unsigned* __restrict__ e_info, float* __restrict__ pooled0) {
    // bijective stripe: gcd(1021, 8965)=1 -> all sections co-resident
    const int bid = (int)(((long long)blockIdx.x * 1021) % B_PREP);
    const int t = threadIdx.x;
    if (bid < B_SCAT) {
        int e = bid * 256 + t;
        if (e < EE) {
            int dst = ei[EE + e];
            int slot = atomicAdd(&epos[dst], 1);
            if (slot < ESTRIDE) {
                unsigned cidx = (unsigned)eattr[e * 3 + 0] | ((unsigned)eattr[e * 3 + 1] << 3)
                              | ((unsigned)eattr[e * 3 + 2] << 6);
                e_info[dst * ESTRIDE + slot] = (unsigned)ei[e] | (cidx << 16);
            }
        }
    } else if (bid < B_SCAT + B_COMBO) {
        int e = (bid - B_SCAT) * 256 + t;
        if (e < LL * CPAD * DD) {
            int l = e / (CPAD * DD), rem = e - l * (CPAD * DD);
            int c = rem / DD, d = rem - c * DD;
            float s;
            if (c >= 512) s = -1e30f;                     // sentinel rows: relu(x+s)==0
            else {
                const float* b_ = bond + (size_t)l * 3 * 8 * DD;
                s = b_[(c & 7) * DD + d] + b_[(8 + ((c >> 3) & 7)) * DD + d]
                  + b_[(16 + (c >> 6)) * DD + d];
            }
            combo[e] = f2b(s);
        }
    } else if (bid < B_SCAT + B_COMBO + B_WT) {
        __shared__ float tile[32][33];
        int b = bid - B_SCAT - B_COMBO;
        int mat = b >> 4, tl = b & 15;
        int k0 = (tl >> 2) * 32, c0 = (tl & 3) * 32;
        const float* W = (mat < 5) ? (w1 + (size_t)mat * DD * DD)
                                   : (w2 + (size_t)(mat - 5) * DD * DD);
        int j = t & 31, q = t >> 5;
#pragma unroll
        for (int rr = 0; rr < 4; ++rr) {
            int row = q + rr * 8;
            tile[row][j] = W[(size_t)(k0 + row) * DD + c0 + j];
        }
        __syncthreads();
#pragma unroll
        for (int rr = 0; rr < 4; ++rr) {
            int cr = q + rr * 8;
            wt[(size_t)mat * DD * DD + (size_t)(c0 + cr) * DD + k0 + j] = (short)f2b(tile[j][cr]);
        }
    } else if (bid < B_SCAT + B_COMBO + B_WT + B_CVT) {
        int gid = (bid - (B_SCAT + B_COMBO + B_WT)) * 256 + t;
        const float4* xp = (const float4*)(x + (size_t)gid * 8);
        float4 a = xp[0], c4 = xp[1];
        uint4 o;
        o.x = pk2(a.x, a.y); o.y = pk2(a.z, a.w);
        o.z = pk2(c4.x, c4.y); o.w = pk2(c4.z, c4.w);
        ((uint4*)xb4)[gid] = o;
    } else {
        __shared__ float sm[DD];
        int b = bid - (B_SCAT + B_COMBO + B_WT + B_CVT);
        int g = b >> 3, s = b & 7;
        int r0, r1;
        {
            int lo = 0, hi = NN;
            while (lo < hi) { int m = (lo + hi) >> 1; if (batch[m] < g) lo = m + 1; else hi = m; }
            r0 = lo;
            lo = 0; hi = NN;
            while (lo < hi) { int m = (lo + hi) >> 1; if (batch[m] < g + 1) lo = m + 1; else hi = m; }
            r1 = lo;
        }
        int col = t & 127, par = t >> 7;
        float ssum = 0.f;
        for (int r = r0 + s * 2 + par; r < r1; r += 16) ssum += x[(size_t)r * DD + col];
        if (par == 0) sm[col] = ssum;
        __syncthreads();
        if (par == 1) {
            float v = sm[col] + ssum;
            if (v != 0.f) atomicAdd(&pooled0[(size_t)g * DD + col], v);
        }
    }
}

// ====== fused layer: CSR aggregation (phase A) + conv/BN/pool (phase B) ======
// Phase A: TRUE 2-deep pipeline via inline-asm loads + hand-counted vmcnt.
// Rounds 8-10 lesson: the compiler sinks any source-level prefetch to its use
// (VGPR stayed 64, buffers never coexisted). Asm loads are opaque -> cannot be
// sunk; s_waitcnt vmcnt(9) waits for buffer-cur while buffer-nxt's 9 newest
// loads stay in flight (in-order retirement). sched_barrier(0) after each wait
// stops consumer hoisting (rule #18). Compiler waits for ITS loads (degp, tail)
// remain conservative-correct with alien loads in flight (vmcnt counts all).
__launch_bounds__(256, 3)
__global__ void layer_fused(const unsigned short* __restrict__ xin,
                            const int* __restrict__ epos,
                            const unsigned* __restrict__ e_info,
                            const unsigned short* __restrict__ combo,
                            const short* __restrict__ Wt1, const short* __restrict__ Wt2,
                            const float* __restrict__ b1, const float* __restrict__ g1,
                            const float* __restrict__ be1, const float* __restrict__ m1,
                            const float* __restrict__ v1,
                            const float* __restrict__ b2, const float* __restrict__ g2,
                            const float* __restrict__ be2, const float* __restrict__ m2,
                            const float* __restrict__ v2,
                            const int* __restrict__ batch,
                            unsigned short* __restrict__ xout,
                            float* __restrict__ pool_slot) {
    __shared__ short As[32 * 136];
    __shared__ int sbg[32];
    const int tid  = threadIdx.x;
    const int lane = tid & 63;
    const int wave = tid >> 6;
    const int row0 = blockIdx.x * 32;
    const int gmin = batch[row0];

    if (tid < 32) {
        int row = row0 + tid;
        sbg[tid] = (row < NN) ? batch[row] - gmin : -1;
    }

    // ---- phase A ----
    const int eg = lane >> 4;            // slot sub-group 0..3
    const int f  = (lane & 15) * 8;      // feature offset
    const int node0 = row0 + wave * 8;

    // deg prefetch: lane j holds epos[node0 + (j&7)]; dummy use forces the
    // compiler's vmcnt wait for it to land HERE (before our asm loads).
    int degp;
    {
        int nk = node0 + (lane & 7);
        if (nk >= NN) nk = NN - 1;
        degp = epos[nk];
    }
    asm volatile("" :: "v"(degp));

    // e_info prefetch: 8 asm loads, drained before address use
    uint4e ev[8];
#pragma unroll
    for (int k = 0; k < 8; ++k) {
        int nk = node0 + k;
        if (nk >= NN) nk = NN - 1;
        GLD(ev[k], (const void*)&e_info[(size_t)nk * ESTRIDE + eg * 4]);
    }
    asm volatile("s_waitcnt vmcnt(0)" ::: "memory");
    __builtin_amdgcn_sched_barrier(0);

    // double-buffered gather registers (+ self row); 9 asm loads per node
    uint4e xg[2][4], cg[2][4], sf[2];
#define GATHER(B, K)                                                              \
    do {                                                                          \
        GLD(xg[B][0], (const void*)&xin[(size_t)(ev[K].x & 0xFFFFu) * DD + f]);   \
        GLD(cg[B][0], (const void*)&combo[(size_t)(ev[K].x >> 16) * DD + f]);     \
        GLD(xg[B][1], (const void*)&xin[(size_t)(ev[K].y & 0xFFFFu) * DD + f]);   \
        GLD(cg[B][1], (const void*)&combo[(size_t)(ev[K].y >> 16) * DD + f]);     \
        GLD(xg[B][2], (const void*)&xin[(size_t)(ev[K].z & 0xFFFFu) * DD + f]);   \
        GLD(cg[B][2], (const void*)&combo[(size_t)(ev[K].z >> 16) * DD + f]);     \
        GLD(xg[B][3], (const void*)&xin[(size_t)(ev[K].w & 0xFFFFu) * DD + f]);   \
        GLD(cg[B][3], (const void*)&combo[(size_t)(ev[K].w >> 16) * DD + f]);     \
        int nkk = node0 + (K); if (nkk >= NN) nkk = NN - 1;                       \
        GLD(sf[B], (const void*)&xin[(size_t)nkk * DD + f]);                      \
    } while (0)

    GATHER(0, 0);
#pragma unroll
    for (int k = 0; k < 8; ++k) {
        const int cur = k & 1;
        const int nxt = cur ^ 1;
        if (k < 7) {
            GATHER(nxt, k + 1);          // 9 newest in-flight loads = next node's
            asm volatile("s_waitcnt vmcnt(9)" ::: "memory");
        } else {
            asm volatile("s_waitcnt vmcnt(0)" ::: "memory");
        }
        __builtin_amdgcn_sched_barrier(0);   // rule #18: pin consumer below wait

        float acc[8];
#pragma unroll
        for (int i = 0; i < 8; ++i) acc[i] = 0.f;
        acc8(acc, xg[cur][0], cg[cur][0]);
        acc8(acc, xg[cur][1], cg[cur][1]);
        acc8(acc, xg[cur][2], cg[cur][2]);
        acc8(acc, xg[cur][3], cg[cur][3]);

        const int nl = wave * 8 + k;
        const int node = row0 + nl;
        int deg = __shfl(degp, k, 64);
        if (deg > 16 && node < NN) {     // ~10% of nodes; slow path (compiler loads)
            if (deg > ESTRIDE) deg = ESTRIDE;
            const int base = node * ESTRIDE;
            const int pe = base + ((deg + 7) & ~7);
            for (int p = base + 16; p < pe; p += 8) {
                // 8 slots; this lane takes {p+2eg, p+2eg+1}
                uint2 jv = *(const uint2*)&e_info[p + eg * 2];
                uint4 ax0 = *(const uint4*)&xin[(size_t)(jv.x & 0xFFFFu) * DD + f];
                uint4 ac0 = *(const uint4*)&combo[(size_t)(jv.x >> 16) * DD + f];
                uint4 ax1 = *(const uint4*)&xin[(size_t)(jv.y & 0xFFFFu) * DD + f];
                uint4 ac1 = *(const uint4*)&combo[(size_t)(jv.y >> 16) * DD + f];
                acc8u(acc, ax0, ac0);
                acc8u(acc, ax1, ac1);
            }
        }

        // reduce across the 4 slot sub-groups (lanes differing in bits 4,5)
#pragma unroll
        for (int i = 0; i < 8; ++i) {
            acc[i] += __shfl_xor(acc[i], 16, 64);
            acc[i] += __shfl_xor(acc[i], 32, 64);
        }
        if (lane < 16) {
            if (node < NN) {
                uint4e self = sf[cur];
                uint4 o;
                o.x = pk2(acc[0] + blo(self.x), acc[1] + bhi(self.x));
                o.y = pk2(acc[2] + blo(self.y), acc[3] + bhi(self.y));
                o.z = pk2(acc[4] + blo(self.z), acc[5] + bhi(self.z));
                o.w = pk2(acc[6] + blo(self.w), acc[7] + bhi(self.w));
                *(uint4*)&As[nl * 136 + f] = o;
            } else {
                *(uint4*)&As[nl * 136 + f] = make_uint4(0, 0, 0, 0);
            }
        }
    }
#undef GATHER
    __syncthreads();

    // ---- phase B: conv + BN + pooling (reads As) ----
    const int col   = wave * 32 + (lane & 31);
    const int khalf = (lane >> 5) * 8;
    const int arow  = lane & 31;
    const int rbase = 4 * (lane >> 5);

    short8 bf[8];
#pragma unroll
    for (int ch = 0; ch < 8; ++ch)
        bf[ch] = *(const short8*)&Wt1[col * DD + ch * 16 + khalf];

    const float sc1 = g1[col] * rsqrtf(v1[col] + BN_EPS);
    const float sh1 = fmaf(b1[col] - m1[col], sc1, be1[col]);
    const float sc2 = g2[col] * rsqrtf(v2[col] + BN_EPS);
    const float sh2 = fmaf(b2[col] - m2[col], sc2, be2[col]);

    float16 acc0 = {0.f,0.f,0.f,0.f,0.f,0.f,0.f,0.f,0.f,0.f,0.f,0.f,0.f,0.f,0.f,0.f};
#pragma unroll
    for (int ch = 0; ch < 8; ++ch) {
        short8 a0 = *(const short8*)&As[arow * 136 + ch * 16 + khalf];
        acc0 = __builtin_amdgcn_mfma_f32_32x32x16_bf16(a0, bf[ch], acc0, 0, 0, 0);
    }

#pragma unroll
    for (int ch = 0; ch < 8; ++ch)
        bf[ch] = *(const short8*)&Wt2[col * DD + ch * 16 + khalf];

    __syncthreads();
#pragma unroll
    for (int r = 0; r < 16; ++r) {
        int rl = (r & 3) + 8 * (r >> 2) + rbase;
        As[rl * 136 + col] = (short)f2b(fmaxf(fmaf(acc0[r], sc1, sh1), 0.f));
    }
    __syncthreads();

    acc0 = float16{0.f,0.f,0.f,0.f,0.f,0.f,0.f,0.f,0.f,0.f,0.f,0.f,0.f,0.f,0.f,0.f};
#pragma unroll
    for (int ch = 0; ch < 8; ++ch) {
        short8 a0 = *(const short8*)&As[arow * 136 + ch * 16 + khalf];
        acc0 = __builtin_amdgcn_mfma_f32_32x32x16_bf16(a0, bf[ch], acc0, 0, 0, 0);
    }

    float pg0 = 0.f, pg1 = 0.f, pg2 = 0.f, pg3 = 0.f;
#pragma unroll
    for (int r = 0; r < 16; ++r) {
        int rl  = (r & 3) + 8 * (r >> 2) + rbase;
        int row = row0 + rl;
        float v0 = fmaxf(fmaf(acc0[r], sc2, sh2), 0.f);
        if (row < NN) xout[(size_t)row * DD + col] = f2b(v0);
        int ga = sbg[rl];
        pg0 += (ga == 0) ? v0 : 0.f;
        pg1 += (ga == 1) ? v0 : 0.f;
        pg2 += (ga == 2) ? v0 : 0.f;
        pg3 += (ga == 3) ? v0 : 0.f;
    }
    pg0 += __shfl_down(pg0, 32);
    pg1 += __shfl_down(pg1, 32);
    pg2 += __shfl_down(pg2, 32);
    pg3 += __shfl_down(pg3, 32);
    if (lane < 32) {
        if (pg0 != 0.f)                  atomicAdd(&pool_slot[(gmin    ) * DD + col], pg0);
        if (pg1 != 0.f && gmin + 1 < GG) atomicAdd(&pool_slot[(gmin + 1) * DD + col], pg1);
        if (pg2 != 0.f && gmin + 2 < GG) atomicAdd(&pool_slot[(gmin + 2) * DD + col], pg2);
        if (pg3 != 0.f && gmin + 3 < GG) atomicAdd(&pool_slot[(gmin + 3) * DD + col], pg3);
    }
}

// ====== final head: out[g,:] = inv[g]*sum_l pooled_l@fcw_l + sum_l fcb_l ======
__launch_bounds__(64)
__global__ void head(const int* __restrict__ batch, const float* __restrict__ pooled,
                     const float* __restrict__ fcw, const float* __restrict__ fcb,
                     float* __restrict__ out) {
    int g = blockIdx.x, t = threadIdx.x;
    __shared__ float part[LL + 1][OO];
    int r0, r1;
    {
        int lo = 0, hi = NN;
        while (lo < hi) { int m = (lo + hi) >> 1; if (batch[m] < g) lo = m + 1; else hi = m; }
        r0 = lo;
        lo = 0; hi = NN;
        while (lo < hi) { int m = (lo + hi) >> 1; if (batch[m] < g + 1) lo = m + 1; else hi = m; }
        r1 = lo;
    }
    const float invg = 1.0f / fmaxf((float)(r1 - r0), 1.0f);
    if (t < (LL + 1) * OO) {
        int l = t / OO, o2 = t - l * OO;
        const float* p = pooled + ((size_t)l * GG + g) * DD;
        const float* w = fcw + (size_t)l * DD * OO + o2;
        float s = 0.f;
        for (int d2 = 0; d2 < DD; ++d2) s = fmaf(p[d2], w[(size_t)d2 * OO], s);
        part[l][o2] = s;
    }
    __syncthreads();
    if (t < OO) {
        float sp = 0.f, sb2 = 0.f;
#pragma unroll
        for (int l = 0; l < LL + 1; ++l) { sp += part[l][t]; sb2 += fcb[l * OO + t]; }
        out[g * OO + t] = sp * invg + sb2;
    }
}

extern "C" void kernel_launch(void* const* d_in, const int* in_sizes, int n_in,
                              void* d_out, int out_size, void* d_ws, size_t ws_size,
                              hipStream_t stream) {
    const float* x_in    = (const float*)d_in[0];
    const int*   ei      = (const int*)d_in[1];
    const int*   eattr   = (const int*)d_in[2];
    const int*   batch   = (const int*)d_in[3];
    const float* bond    = (const float*)d_in[4];
    const float* conv_w1 = (const float*)d_in[5];
    const float* conv_b1 = (const float*)d_in[6];
    const float* cbg     = (const float*)d_in[7];
    const float* cbb     = (const float*)d_in[8];
    const float* cbm     = (const float*)d_in[9];
    const float* cbv     = (const float*)d_in[10];
    const float* conv_w2 = (const float*)d_in[11];
    const float* conv_b2 = (const float*)d_in[12];
    const float* bg      = (const float*)d_in[13];
    const float* bb      = (const float*)d_in[14];
    const float* bm      = (const float*)d_in[15];
    const float* bv      = (const float*)d_in[16];
    const float* fcw     = (const float*)d_in[17];
    const float* fcb     = (const float*)d_in[18];
    float* out = (float*)d_out;

    // ---- workspace carve-up (16B-aligned chunks) ----
    char* base = (char*)d_ws;
    size_t o = 0;
    auto carve = [&](size_t bytes) { void* p = base + o; o += (bytes + 15) & ~(size_t)15; return p; };
    unsigned short* xbA    = (unsigned short*)carve((size_t)NN * DD * 2);
    unsigned short* xbB    = (unsigned short*)carve((size_t)NN * DD * 2);
    unsigned short* combo  = (unsigned short*)carve((size_t)LL * CPAD * DD * 2);
    short*          wt     = (short*)carve((size_t)10 * DD * DD * 2);
    // contiguous zero-region: epos | pooled[6][G][D] (slot 0 = pool0)
    const size_t ZBYTES = (size_t)NN * 4 + (size_t)(LL + 1) * GG * DD * 4;
    int*            epos   = (int*)carve(ZBYTES);
    float*          pooled = (float*)((char*)epos + (size_t)NN * 4);
    unsigned*       e_info = (unsigned*)carve((size_t)NN * ESTRIDE * 4);

    (void)hipMemsetAsync(epos, 0, ZBYTES, stream);
    (void)hipMemsetAsync(e_info, 0x02, (size_t)NN * ESTRIDE * 4, stream);  // sentinel fill

    prep<<<B_PREP, 256, 0, stream>>>(x_in, ei, eattr, batch, bond, conv_w1, conv_w2,
                                     (unsigned*)xbA, combo, wt, epos, e_info, pooled);

    const int layer_blocks = (NN + 31) / 32;    // 1563
    unsigned short* xcur = xbA;   // layer input (complete previous activation)
    unsigned short* xnxt = xbB;   // layer output (ping-pong; in-place would race)
    for (int i = 0; i < LL; ++i) {
        layer_fused<<<layer_blocks, 256, 0, stream>>>(
            xcur, epos, e_info, combo + (size_t)i * CPAD * DD,
            wt + (size_t)i * DD * DD, wt + (size_t)(5 + i) * DD * DD,
            conv_b1 + (size_t)i * DD, cbg + (size_t)i * DD, cbb + (size_t)i * DD,
            cbm + (size_t)i * DD, cbv + (size_t)i * DD,
            conv_b2 + (size_t)i * DD, bg + (size_t)i * DD, bb + (size_t)i * DD,
            bm + (size_t)i * DD, bv + (size_t)i * DD,
            batch, xnxt, pooled + (size_t)(i + 1) * GG * DD);
        unsigned short* tmp = xcur; xcur = xnxt; xnxt = tmp;
    }
    head<<<GG, 64, 0, stream>>>(batch, pooled, fcw, fcb, out);
}